// Round 1
// baseline (522.831 us; speedup 1.0000x reference)
//
#include <hip/hip_runtime.h>
#include <hip/hip_bf16.h>
#include <math.h>

typedef __attribute__((ext_vector_type(8))) short bf16x8;
typedef __attribute__((ext_vector_type(4))) float f32x4;

#define NCLS   50000
#define KSUB   3
#define DIM    512
#define NROWSW (NCLS*KSUB)   // 150000
#define BQ     1024

#define SCALEF 30.0f
#define EPSC   1e-7f
#define COSM   0.8775825618903728f
#define SINM   0.4794255386042030f

#define BN     48            // weight rows per LDS tile (multiple of 48 = lcm(16,3))
#define TW     3             // 16-row MFMA tiles per weight tile
#define WAVES  8
#define NBJ    2             // 16-wide b subtiles per wave
#define CHUNKS 4             // 1024 / (WAVES*16*NBJ)
#define NTILES (NROWSW/BN)   // 3125 exactly
#define NBLK   625           // each block processes exactly 5 tiles

__device__ __forceinline__ float wave_sum(float v) {
#pragma unroll
  for (int m = 1; m < 64; m <<= 1) v += __shfl_xor(v, m, 64);
  return v;
}

__device__ __forceinline__ short f2bf(float x) {  // RNE f32 -> bf16
  unsigned u = __float_as_uint(x);
  u += 0x7fffu + ((u >> 16) & 1u);
  return (short)(u >> 16);
}

__device__ __forceinline__ float eterm(float v) {
  v = fminf(fmaxf(v, -1.f + EPSC), 1.f - EPSC);
  return __expf(SCALEF * v);
}

// K0: normalize embeddings, store bf16 [1024][512]
__global__ __launch_bounds__(64) void k_norm_e(const float* __restrict__ E,
                                               short* __restrict__ En) {
  const int b = blockIdx.x, l = threadIdx.x;
  const float4* p = reinterpret_cast<const float4*>(E + (size_t)b * DIM + l * 8);
  float4 a = p[0], c = p[1];
  float ss = a.x*a.x + a.y*a.y + a.z*a.z + a.w*a.w
           + c.x*c.x + c.y*c.y + c.z*c.z + c.w*c.w;
  ss = wave_sum(ss);
  float inv = rsqrtf(ss);
  bf16x8 o;
  o[0]=f2bf(a.x*inv); o[1]=f2bf(a.y*inv); o[2]=f2bf(a.z*inv); o[3]=f2bf(a.w*inv);
  o[4]=f2bf(c.x*inv); o[5]=f2bf(c.y*inv); o[6]=f2bf(c.z*inv); o[7]=f2bf(c.w*inv);
  *reinterpret_cast<bf16x8*>(En + (size_t)b * DIM + l * 8) = o;
}

// K2: exact f32 target-class cosine + margin terms (1 wave per batch row)
__global__ __launch_bounds__(64) void k_target(const float* __restrict__ E,
                                               const int* __restrict__ lab,
                                               const float* __restrict__ W,
                                               float* __restrict__ delta,
                                               float* __restrict__ tl) {
  const int b = blockIdx.x, l = threadIdx.x;
  const float4* pe = reinterpret_cast<const float4*>(E + (size_t)b * DIM + l * 8);
  float4 e0 = pe[0], e1 = pe[1];
  float es = e0.x*e0.x + e0.y*e0.y + e0.z*e0.z + e0.w*e0.w
           + e1.x*e1.x + e1.y*e1.y + e1.z*e1.z + e1.w*e1.w;
  es = wave_sum(es);
  const int L = lab[b];
  float mx = -2.f;
#pragma unroll
  for (int k = 0; k < KSUB; ++k) {
    const float4* pw = reinterpret_cast<const float4*>(W + (size_t)(L * KSUB + k) * DIM + l * 8);
    float4 w0 = pw[0], w1 = pw[1];
    float ds = e0.x*w0.x + e0.y*w0.y + e0.z*w0.z + e0.w*w0.w
             + e1.x*w1.x + e1.y*w1.y + e1.z*w1.z + e1.w*w1.w;
    float ws = w0.x*w0.x + w0.y*w0.y + w0.z*w0.z + w0.w*w0.w
             + w1.x*w1.x + w1.y*w1.y + w1.z*w1.z + w1.w*w1.w;
    ds = wave_sum(ds);
    ws = wave_sum(ws);
    float ck = ds * rsqrtf(es * ws);
    mx = fmaxf(mx, ck);
  }
  if (l == 0) {
    float cc = fminf(fmaxf(mx, -1.f + EPSC), 1.f - EPSC);
    float sn = sqrtf(fmaxf(1.f - cc * cc, 0.f));
    float mg = cc * COSM - sn * SINM;           // cos(arccos(cc)+m)
    delta[b] = __expf(SCALEF * mg) - __expf(SCALEF * cc);
    tl[b]    = SCALEF * mg;
  }
}

// K1: main — per weight tile: normalize->bf16->swizzled LDS; MFMA C = W x E^T;
// in-register max-over-3-subcenters via rotate-16 shuffle; exp; per-b partials.
__global__ __launch_bounds__(512) void k_main(const float* __restrict__ W,
                                              const short* __restrict__ En,
                                              float* __restrict__ Zp) {
  __shared__ __align__(16) short wlds[BN * DIM];  // 48 KB, XOR-swizzled 16B chunks
  const int tid  = threadIdx.x;
  const int lane = tid & 63;
  const int wv   = tid >> 6;
  const int g    = lane >> 4;    // 4-row granule group
  const int c    = lane & 15;    // output column (b) / A row within tile

  float zreg[CHUNKS][NBJ];
#pragma unroll
  for (int ch = 0; ch < CHUNKS; ++ch)
#pragma unroll
    for (int j = 0; j < NBJ; ++j) zreg[ch][j] = 0.f;

  const bf16x8* wl8 = reinterpret_cast<const bf16x8*>(wlds);

  for (int tile = blockIdx.x; tile < NTILES; tile += NBLK) {
    // ---- stage: load 48 weight rows, normalize, bf16, swizzled LDS write ----
#pragma unroll
    for (int i = 0; i < BN / WAVES; ++i) {     // 6 rows per wave
      const int lr = wv * (BN / WAVES) + i;
      const float4* p = reinterpret_cast<const float4*>(
          W + ((size_t)tile * BN + lr) * DIM + lane * 8);
      float4 a = p[0], d = p[1];
      float ss = a.x*a.x + a.y*a.y + a.z*a.z + a.w*a.w
               + d.x*d.x + d.y*d.y + d.z*d.z + d.w*d.w;
      ss = wave_sum(ss);
      float inv = rsqrtf(ss);
      bf16x8 o;
      o[0]=f2bf(a.x*inv); o[1]=f2bf(a.y*inv); o[2]=f2bf(a.z*inv); o[3]=f2bf(a.w*inv);
      o[4]=f2bf(d.x*inv); o[5]=f2bf(d.y*inv); o[6]=f2bf(d.z*inv); o[7]=f2bf(d.w*inv);
      const int cb = lane ^ (lr & 7);          // data chunk `lane` -> swizzled slot
      reinterpret_cast<bf16x8*>(wlds)[lr * 64 + cb] = o;
    }
    __syncthreads();

    // ---- compute ----
#pragma unroll
    for (int ch = 0; ch < CHUNKS; ++ch) {
      const int bbase = ch * 256 + wv * 32;
      f32x4 acc[TW][NBJ];
#pragma unroll
      for (int t = 0; t < TW; ++t)
#pragma unroll
        for (int j = 0; j < NBJ; ++j) acc[t][j] = (f32x4){0.f, 0.f, 0.f, 0.f};

#pragma unroll 4
      for (int ks = 0; ks < DIM / 32; ++ks) {
        bf16x8 bfr[NBJ];
#pragma unroll
        for (int j = 0; j < NBJ; ++j)
          bfr[j] = *reinterpret_cast<const bf16x8*>(
              En + (size_t)(bbase + j * 16 + c) * DIM + ks * 32 + g * 8);
#pragma unroll
        for (int t = 0; t < TW; ++t) {
          const int lr = t * 16 + c;
          bf16x8 af = wl8[lr * 64 + ((ks * 4 + g) ^ (lr & 7))];
#pragma unroll
          for (int j = 0; j < NBJ; ++j)
            acc[t][j] = __builtin_amdgcn_mfma_f32_16x16x32_bf16(af, bfr[j], acc[t][j], 0, 0, 0);
        }
      }

      // ---- finalize: max over sub-center triples, exp, per-b sum ----
#pragma unroll
      for (int j = 0; j < NBJ; ++j) {
        float zc = 0.f;
#pragma unroll
        for (int t = 0; t < TW; ++t) {
          // rows held: 16t + 4g + r. Fetch next-granule rows (r=0,1) via rotate-16.
          float s0, s1;
          if (t + 1 < TW) {
            s0 = (g == 0) ? acc[t + 1][j][0] : acc[t][j][0];
            s1 = (g == 0) ? acc[t + 1][j][1] : acc[t][j][1];
          } else {
            s0 = (g == 0) ? -2.f : acc[t][j][0];
            s1 = (g == 0) ? -2.f : acc[t][j][1];
          }
          float e0 = __shfl(s0, (lane + 16) & 63, 64);
          float e1 = __shfl(s1, (lane + 16) & 63, 64);
          const int m = (4 * t + g) % 3;
          float a0 = acc[t][j][0], a1 = acc[t][j][1], a2 = acc[t][j][2], a3 = acc[t][j][3];
          if (m == 0)      zc += eterm(fmaxf(fmaxf(a0, a1), a2)) + eterm(fmaxf(fmaxf(a3, e0), e1));
          else if (m == 1) zc += eterm(fmaxf(fmaxf(a2, a3), e0));
          else             zc += eterm(fmaxf(fmaxf(a1, a2), a3));
        }
        zc += __shfl_xor(zc, 16, 64);
        zc += __shfl_xor(zc, 32, 64);
        zreg[ch][j] += zc;
      }
    }
    __syncthreads();   // before next tile overwrites wlds
  }

  if (g == 0) {
#pragma unroll
    for (int ch = 0; ch < CHUNKS; ++ch)
#pragma unroll
      for (int j = 0; j < NBJ; ++j)
        Zp[(size_t)blockIdx.x * BQ + ch * 256 + wv * 32 + j * 16 + c] = zreg[ch][j];
  }
}

// K3: Z[b] = sum of partials; per-row loss; block partial sums
__global__ __launch_bounds__(256) void k_reduce(const float* __restrict__ Zp,
                                                const float* __restrict__ delta,
                                                const float* __restrict__ tl,
                                                float* __restrict__ part) {
  const int b = blockIdx.x * 256 + threadIdx.x;
  float z = 0.f;
  for (int nb = 0; nb < NBLK; ++nb) z += Zp[(size_t)nb * BQ + b];
  float lossb = logf(z + delta[b]) - tl[b];
  __shared__ float sm[256];
  sm[threadIdx.x] = lossb;
  __syncthreads();
#pragma unroll
  for (int s = 128; s > 0; s >>= 1) {
    if (threadIdx.x < s) sm[threadIdx.x] += sm[threadIdx.x + s];
    __syncthreads();
  }
  if (threadIdx.x == 0) part[blockIdx.x] = sm[0];
}

__global__ void k_final(const float* __restrict__ part, float* __restrict__ out) {
  out[0] = (part[0] + part[1] + part[2] + part[3]) * (1.0f / BQ);
}

extern "C" void kernel_launch(void* const* d_in, const int* in_sizes, int n_in,
                              void* d_out, int out_size, void* d_ws, size_t ws_size,
                              hipStream_t stream) {
  const float* E  = (const float*)d_in[0];
  const int* lab  = (const int*)d_in[1];
  const float* W  = (const float*)d_in[2];

  char* ws = (char*)d_ws;
  short* En    = (short*)ws;                                   // 1 MB
  float* Zp    = (float*)(ws + (size_t)BQ * DIM * 2);          // 625*1024*4 = 2.56 MB
  float* delta = (float*)((char*)Zp + (size_t)NBLK * BQ * 4);  // 4 KB
  float* tl    = delta + BQ;                                   // 4 KB
  float* part  = tl + BQ;                                      // 16 B

  hipLaunchKernelGGL(k_norm_e, dim3(BQ),   dim3(64),  0, stream, E, En);
  hipLaunchKernelGGL(k_target, dim3(BQ),   dim3(64),  0, stream, E, lab, W, delta, tl);
  hipLaunchKernelGGL(k_main,   dim3(NBLK), dim3(512), 0, stream, W, En, Zp);
  hipLaunchKernelGGL(k_reduce, dim3(4),    dim3(256), 0, stream, Zp, delta, tl, part);
  hipLaunchKernelGGL(k_final,  dim3(1),    dim3(1),   0, stream, part, (float*)d_out);
}